// Round 1
// baseline (667.150 us; speedup 1.0000x reference)
//
#include <hip/hip_runtime.h>

// GCN: 3-layer, N=50000 nodes, E=800000 edges, F 128->200->100->40, f32.
// Pipeline per call (all deterministic, CSR rebuilt every call):
//   detect edge dtype -> histogram(dst) -> scan -> CSR place ->
//   gemm1 (x@W1) -> agg1 -> gemm2 (relu(agg1+b1)@W2) -> agg2 ->
//   gemm3 (relu(agg2+b2)@Wout + bout) -> d_out

#define NN 50000
#define NE 800000
#define FIN 128
#define HH1 200
#define HH2 100
#define NCLS 40

static __device__ __forceinline__ long long edge_at(const void* p, int is64, long long pos) {
    if (is64) return ((const long long*)p)[pos];
    return (long long)((const int*)p)[pos];
}

// Detect whether edge_index buffer is int64 (odd 32-bit words are the upper
// halves of values < 50000 -> all zero) or int32 (odd words are random
// indices, nonzero w.h.p.).
__global__ void detect_kernel(const unsigned int* __restrict__ w, int* __restrict__ flag) {
    int is64 = 1;
    for (int i = 0; i < 32; ++i)
        if (w[2 * i + 1] != 0u) { is64 = 0; break; }
    *flag = is64;
}

__global__ void init_kernel(int* __restrict__ cnt, int* __restrict__ cursor, int n) {
    int i = blockIdx.x * blockDim.x + threadIdx.x;
    if (i < n) { cnt[i] = 0; cursor[i] = 0; }
}

__global__ void hist_kernel(const void* __restrict__ ei, const int* __restrict__ flag,
                            int* __restrict__ cnt, int E) {
    int e = blockIdx.x * blockDim.x + threadIdx.x;
    if (e < E) {
        int is64 = *flag;
        int d = (int)edge_at(ei, is64, (long long)E + e);
        atomicAdd(&cnt[d], 1);
    }
}

// Single-block exclusive scan over 50000 bins + dinv = rsqrt(deg+1).
__global__ __launch_bounds__(1024)
void scan_kernel(const int* __restrict__ cnt, int* __restrict__ row_start,
                 float* __restrict__ dinv, int n) {
    __shared__ int sdata[1024];
    __shared__ int carry_s;
    int t = threadIdx.x;
    if (t == 0) carry_s = 0;
    __syncthreads();
    for (int base = 0; base < n; base += 1024) {
        int i = base + t;
        int v = (i < n) ? cnt[i] : 0;
        if (i < n) dinv[i] = rsqrtf((float)(v + 1));
        sdata[t] = v;
        __syncthreads();
        #pragma unroll
        for (int offd = 1; offd < 1024; offd <<= 1) {
            int tv = (t >= offd) ? sdata[t - offd] : 0;
            __syncthreads();
            sdata[t] += tv;
            __syncthreads();
        }
        int carry = carry_s;
        if (i < n) row_start[i] = carry + sdata[t] - v;   // exclusive
        __syncthreads();
        if (t == 1023) carry_s = carry + sdata[1023];
        __syncthreads();
    }
    if (t == 0) row_start[n] = carry_s;
}

__global__ void place_kernel(const void* __restrict__ ei, const int* __restrict__ flag,
                             const int* __restrict__ row_start, int* __restrict__ cursor,
                             const float* __restrict__ dinv, int* __restrict__ csr_src,
                             float* __restrict__ csr_w, int E) {
    int e = blockIdx.x * blockDim.x + threadIdx.x;
    if (e < E) {
        int is64 = *flag;
        int s = (int)edge_at(ei, is64, e);
        int d = (int)edge_at(ei, is64, (long long)E + e);
        int p = atomicAdd(&cursor[d], 1);
        int slot = row_start[d] + p;
        csr_src[slot] = s;
        csr_w[slot] = dinv[s] * dinv[d];
    }
}

// Tiled f32 GEMM: C[M,N] = actA(A)[M,K] @ B[K,N] (+ biasC).
// actA(a) = RELUA ? max(a + biasA[k], 0) : a   (fused previous layer's bias+relu)
template <bool RELUA, bool BIASC>
__global__ __launch_bounds__(256)
void gemm_kernel(const float* __restrict__ A, const float* __restrict__ B,
                 float* __restrict__ C, const float* __restrict__ biasA,
                 const float* __restrict__ biasC, int M, int N, int K) {
    constexpr int BM = 64, BN = 64, BK = 32, PAD = 4;
    __shared__ __align__(16) float As[BK][BM + PAD];
    __shared__ __align__(16) float Bs[BK][BN + PAD];
    const int tid = threadIdx.x;
    const int tx = tid & 15;   // col group (x4)
    const int ty = tid >> 4;   // row group (x4)
    const int bm = blockIdx.y * BM;
    const int bn = blockIdx.x * BN;
    float acc[4][4] = {};

    for (int k0 = 0; k0 < K; k0 += BK) {
        #pragma unroll
        for (int i = 0; i < 8; ++i) {             // A tile: BM x BK
            int lin = tid + i * 256;
            int m = lin >> 5, k = lin & 31;
            int gm = bm + m, gk = k0 + k;
            float a = 0.f;
            if (gm < M && gk < K) {
                a = A[(size_t)gm * K + gk];
                if (RELUA) a = fmaxf(a + biasA[gk], 0.f);
            }
            As[k][m] = a;
        }
        #pragma unroll
        for (int i = 0; i < 8; ++i) {             // B tile: BK x BN
            int lin = tid + i * 256;
            int k = lin >> 6, n = lin & 63;
            int gk = k0 + k, gn = bn + n;
            float b = 0.f;
            if (gk < K && gn < N) b = B[(size_t)gk * N + gn];
            Bs[k][n] = b;
        }
        __syncthreads();
        #pragma unroll
        for (int k = 0; k < BK; ++k) {
            float4 av = *(const float4*)(&As[k][ty * 4]);
            float4 bv = *(const float4*)(&Bs[k][tx * 4]);
            float a4[4] = {av.x, av.y, av.z, av.w};
            float b4[4] = {bv.x, bv.y, bv.z, bv.w};
            #pragma unroll
            for (int i = 0; i < 4; ++i)
                #pragma unroll
                for (int j = 0; j < 4; ++j)
                    acc[i][j] += a4[i] * b4[j];
        }
        __syncthreads();
    }
    #pragma unroll
    for (int i = 0; i < 4; ++i) {
        int gm = bm + ty * 4 + i;
        if (gm >= M) continue;
        #pragma unroll
        for (int j = 0; j < 4; ++j) {
            int gn = bn + tx * 4 + j;
            if (gn >= N) continue;
            float v = acc[i][j];
            if (BIASC) v += biasC[gn];
            C[(size_t)gm * N + gn] = v;
        }
    }
}

// CSR aggregation: out[row] = dinv[row]^2 * hw[row] + sum_e w_e * hw[src_e]
template <int F, int NT>
__global__ __launch_bounds__(NT)
void agg_kernel(const float* __restrict__ hw, const float* __restrict__ dinv,
                const int* __restrict__ row_start, const int* __restrict__ csr_src,
                const float* __restrict__ csr_w, float* __restrict__ out) {
    const int row = blockIdx.x;
    const int j = threadIdx.x;
    const int s0 = row_start[row], s1 = row_start[row + 1];
    float di = dinv[row];
    float acc = 0.f;
    if (j < F) acc = di * di * hw[(size_t)row * F + j];
    for (int e = s0; e < s1; ++e) {
        int s = csr_src[e];
        float w = csr_w[e];
        if (j < F) acc += w * hw[(size_t)s * F + j];
    }
    if (j < F) out[(size_t)row * F + j] = acc;
}

extern "C" void kernel_launch(void* const* d_in, const int* in_sizes, int n_in,
                              void* d_out, int out_size, void* d_ws, size_t ws_size,
                              hipStream_t stream) {
    const float* x    = (const float*)d_in[0];
    const void*  ei   = d_in[1];
    const float* W1   = (const float*)d_in[2];
    const float* b1   = (const float*)d_in[3];
    const float* W2   = (const float*)d_in[4];
    const float* b2   = (const float*)d_in[5];
    const float* Wout = (const float*)d_in[6];
    const float* bout = (const float*)d_in[7];
    float* out = (float*)d_out;

    char* ws = (char*)d_ws;
    size_t off = 0;
    auto alloc = [&](size_t bytes) -> void* {
        off = (off + 255) & ~(size_t)255;
        void* p = ws + off;
        off += bytes;
        return p;
    };
    int*   flag      = (int*)alloc(4);
    int*   cnt       = (int*)alloc((size_t)NN * 4);
    int*   cursor    = (int*)alloc((size_t)NN * 4);
    int*   row_start = (int*)alloc((size_t)(NN + 1) * 4);
    int*   csr_src   = (int*)alloc((size_t)NE * 4);
    float* csr_w     = (float*)alloc((size_t)NE * 4);
    float* dinv      = (float*)alloc((size_t)NN * 4);
    float* buf1      = (float*)alloc((size_t)NN * HH1 * 4);
    float* buf2      = (float*)alloc((size_t)NN * HH1 * 4);
    (void)ws_size; (void)in_sizes; (void)n_in; (void)out_size;

    detect_kernel<<<1, 1, 0, stream>>>((const unsigned int*)ei, flag);
    init_kernel<<<(NN + 255) / 256, 256, 0, stream>>>(cnt, cursor, NN);
    hist_kernel<<<(NE + 255) / 256, 256, 0, stream>>>(ei, flag, cnt, NE);
    scan_kernel<<<1, 1024, 0, stream>>>(cnt, row_start, dinv, NN);
    place_kernel<<<(NE + 255) / 256, 256, 0, stream>>>(ei, flag, row_start, cursor,
                                                       dinv, csr_src, csr_w, NE);
    // gemm1: buf1 = x @ W1   [NN, HH1]
    dim3 g1((HH1 + 63) / 64, (NN + 63) / 64);
    gemm_kernel<false, false><<<g1, 256, 0, stream>>>(x, W1, buf1, nullptr, nullptr,
                                                      NN, HH1, FIN);
    // agg1: buf2 = A_hat @ buf1
    agg_kernel<HH1, 256><<<NN, 256, 0, stream>>>(buf1, dinv, row_start, csr_src, csr_w, buf2);
    // gemm2: buf1 = relu(buf2 + b1) @ W2  [NN, HH2]
    dim3 g2((HH2 + 63) / 64, (NN + 63) / 64);
    gemm_kernel<true, false><<<g2, 256, 0, stream>>>(buf2, W2, buf1, b1, nullptr,
                                                     NN, HH2, HH1);
    // agg2: buf2 = A_hat @ buf1  [NN, HH2]
    agg_kernel<HH2, 128><<<NN, 128, 0, stream>>>(buf1, dinv, row_start, csr_src, csr_w, buf2);
    // gemm3: out = relu(buf2 + b2) @ Wout + bout  [NN, NCLS]
    dim3 g3((NCLS + 63) / 64, (NN + 63) / 64);
    gemm_kernel<true, true><<<g3, 256, 0, stream>>>(buf2, Wout, out, b2, bout,
                                                    NN, NCLS, HH2);
}

// Round 2
// 470.684 us; speedup vs baseline: 1.4174x; 1.4174x over previous
//
#include <hip/hip_runtime.h>

// GCN: 3-layer, N=50000 nodes, E=800000 edges, F 128->200->100->40, f32.
// Pipeline: detect edge dtype -> histogram(dst) -> 3-phase scan -> CSR place
//   -> gemm1 (x@W1) -> agg1 -> gemm2 (relu(+b1)@W2) -> agg2
//   -> gemm3 (relu(+b2)@Wout + bout) -> d_out
// agg: wave-per-row, vectorized lanes, edge loop unrolled x4 for MLP
// (memory-level parallelism) -- R1 showed agg latency-bound (VALUBusy 7%).

#define NN 50000
#define NE 800000
#define FIN 128
#define HH1 200
#define HH2 100
#define NCLS 40

static __device__ __forceinline__ long long edge_at(const void* p, int is64, long long pos) {
    if (is64) return ((const long long*)p)[pos];
    return (long long)((const int*)p)[pos];
}

// Detect whether edge_index buffer is int64 (odd 32-bit words all zero since
// indices < 50000) or int32.
__global__ void detect_kernel(const unsigned int* __restrict__ w, int* __restrict__ flag) {
    int is64 = 1;
    for (int i = 0; i < 32; ++i)
        if (w[2 * i + 1] != 0u) { is64 = 0; break; }
    *flag = is64;
}

__global__ void init_kernel(int* __restrict__ cnt, int* __restrict__ cursor, int n) {
    int i = blockIdx.x * blockDim.x + threadIdx.x;
    if (i < n) { cnt[i] = 0; cursor[i] = 0; }
}

__global__ void hist_kernel(const void* __restrict__ ei, const int* __restrict__ flag,
                            int* __restrict__ cnt, int E) {
    int e = blockIdx.x * blockDim.x + threadIdx.x;
    if (e < E) {
        int is64 = *flag;
        int d = (int)edge_at(ei, is64, (long long)E + e);
        atomicAdd(&cnt[d], 1);
    }
}

// ---- 3-phase exclusive scan over 50000 bins (+ dinv = rsqrt(deg+1)) ----
__global__ __launch_bounds__(1024)
void scan_part_kernel(const int* __restrict__ cnt, int* __restrict__ row_start,
                      float* __restrict__ dinv, int* __restrict__ bsum, int n) {
    __shared__ int sdata[1024];
    const int t = threadIdx.x;
    const int i = blockIdx.x * 1024 + t;
    int v = (i < n) ? cnt[i] : 0;
    if (i < n) dinv[i] = rsqrtf((float)(v + 1));
    sdata[t] = v;
    __syncthreads();
    #pragma unroll
    for (int o = 1; o < 1024; o <<= 1) {
        int tv = (t >= o) ? sdata[t - o] : 0;
        __syncthreads();
        sdata[t] += tv;
        __syncthreads();
    }
    if (i < n) row_start[i] = sdata[t] - v;   // local exclusive
    if (t == 1023) bsum[blockIdx.x] = sdata[1023];
}

__global__ void scan_bsum_kernel(int* __restrict__ bsum, int nb,
                                 int* __restrict__ row_start, int n) {
    if (threadIdx.x == 0 && blockIdx.x == 0) {
        int acc = 0;
        for (int b = 0; b < nb; ++b) { int v = bsum[b]; bsum[b] = acc; acc += v; }
        row_start[n] = acc;
    }
}

__global__ __launch_bounds__(1024)
void scan_add_kernel(int* __restrict__ row_start, const int* __restrict__ bsum, int n) {
    int i = blockIdx.x * 1024 + threadIdx.x;
    if (i < n) row_start[i] += bsum[blockIdx.x];
}

// CSR entry: {src, float_bits(dinv[src]*dinv[dst])} -- one 8B load per edge.
__global__ void place_kernel(const void* __restrict__ ei, const int* __restrict__ flag,
                             const int* __restrict__ row_start, int* __restrict__ cursor,
                             const float* __restrict__ dinv, int2* __restrict__ csr, int E) {
    int e = blockIdx.x * blockDim.x + threadIdx.x;
    if (e < E) {
        int is64 = *flag;
        int s = (int)edge_at(ei, is64, e);
        int d = (int)edge_at(ei, is64, (long long)E + e);
        int p = atomicAdd(&cursor[d], 1);
        csr[row_start[d] + p] = make_int2(s, __float_as_int(dinv[s] * dinv[d]));
    }
}

// Tiled f32 GEMM: C[M,N] = actA(A)[M,K] @ B[K,N] (+ biasC).
template <bool RELUA, bool BIASC>
__global__ __launch_bounds__(256)
void gemm_kernel(const float* __restrict__ A, const float* __restrict__ B,
                 float* __restrict__ C, const float* __restrict__ biasA,
                 const float* __restrict__ biasC, int M, int N, int K) {
    constexpr int BM = 64, BN = 64, BK = 32, PAD = 4;
    __shared__ __align__(16) float As[BK][BM + PAD];
    __shared__ __align__(16) float Bs[BK][BN + PAD];
    const int tid = threadIdx.x;
    const int tx = tid & 15;
    const int ty = tid >> 4;
    const int bm = blockIdx.y * BM;
    const int bn = blockIdx.x * BN;
    float acc[4][4] = {};

    for (int k0 = 0; k0 < K; k0 += BK) {
        #pragma unroll
        for (int i = 0; i < 8; ++i) {             // A tile: BM x BK
            int lin = tid + i * 256;
            int m = lin >> 5, k = lin & 31;
            int gm = bm + m, gk = k0 + k;
            float a = 0.f;
            if (gm < M && gk < K) {
                a = A[(size_t)gm * K + gk];
                if (RELUA) a = fmaxf(a + biasA[gk], 0.f);
            }
            As[k][m] = a;
        }
        #pragma unroll
        for (int i = 0; i < 8; ++i) {             // B tile: BK x BN
            int lin = tid + i * 256;
            int k = lin >> 6, n = lin & 63;
            int gk = k0 + k, gn = bn + n;
            float b = 0.f;
            if (gk < K && gn < N) b = B[(size_t)gk * N + gn];
            Bs[k][n] = b;
        }
        __syncthreads();
        #pragma unroll
        for (int k = 0; k < BK; ++k) {
            float4 av = *(const float4*)(&As[k][ty * 4]);
            float4 bv = *(const float4*)(&Bs[k][tx * 4]);
            float a4[4] = {av.x, av.y, av.z, av.w};
            float b4[4] = {bv.x, bv.y, bv.z, bv.w};
            #pragma unroll
            for (int i = 0; i < 4; ++i)
                #pragma unroll
                for (int j = 0; j < 4; ++j)
                    acc[i][j] += a4[i] * b4[j];
        }
        __syncthreads();
    }
    #pragma unroll
    for (int i = 0; i < 4; ++i) {
        int gm = bm + ty * 4 + i;
        if (gm >= M) continue;
        #pragma unroll
        for (int j = 0; j < 4; ++j) {
            int gn = bn + tx * 4 + j;
            if (gn >= N) continue;
            float v = acc[i][j];
            if (BIASC) v += biasC[gn];
            C[(size_t)gm * N + gn] = v;
        }
    }
}

// CSR aggregation, wave-per-row. Lane l holds VW-float column slice.
// out[row] = dinv[row]^2 * hw[row] + sum_e w_e * hw[src_e]
// Edge loop unrolled x4: 4 independent int2 loads + 4 independent row gathers
// in flight (R1 was latency-bound on the dependent src->gather chain).
template <int F, int VW>
__global__ __launch_bounds__(256)
void agg_kernel(const float* __restrict__ hw, const float* __restrict__ dinv,
                const int* __restrict__ row_start, const int2* __restrict__ csr,
                float* __restrict__ out) {
    constexpr int L = F / VW;                       // active lanes per wave
    typedef float fvec __attribute__((ext_vector_type(VW)));
    const int wave = threadIdx.x >> 6;
    const int lane = threadIdx.x & 63;
    const int row = blockIdx.x * 4 + wave;
    if (row >= NN || lane >= L) return;

    const int s0 = row_start[row], s1 = row_start[row + 1];
    const float di = dinv[row];
    const float* __restrict__ rowp = hw + (size_t)row * F + lane * VW;
    fvec acc = *(const fvec*)rowp;
    #pragma unroll
    for (int q = 0; q < VW; ++q) acc[q] *= di * di;

    int e = s0;
    for (; e + 4 <= s1; e += 4) {
        int2 c0 = csr[e], c1 = csr[e + 1], c2 = csr[e + 2], c3 = csr[e + 3];
        fvec r0 = *(const fvec*)(hw + (size_t)c0.x * F + lane * VW);
        fvec r1 = *(const fvec*)(hw + (size_t)c1.x * F + lane * VW);
        fvec r2 = *(const fvec*)(hw + (size_t)c2.x * F + lane * VW);
        fvec r3 = *(const fvec*)(hw + (size_t)c3.x * F + lane * VW);
        float w0 = __int_as_float(c0.y), w1 = __int_as_float(c1.y);
        float w2 = __int_as_float(c2.y), w3 = __int_as_float(c3.y);
        #pragma unroll
        for (int q = 0; q < VW; ++q) {
            acc[q] = fmaf(r0[q], w0, acc[q]);
            acc[q] = fmaf(r1[q], w1, acc[q]);
            acc[q] = fmaf(r2[q], w2, acc[q]);
            acc[q] = fmaf(r3[q], w3, acc[q]);
        }
    }
    for (; e < s1; ++e) {
        int2 c = csr[e];
        fvec r = *(const fvec*)(hw + (size_t)c.x * F + lane * VW);
        float w = __int_as_float(c.y);
        #pragma unroll
        for (int q = 0; q < VW; ++q) acc[q] = fmaf(r[q], w, acc[q]);
    }
    *(fvec*)(out + (size_t)row * F + lane * VW) = acc;
}

extern "C" void kernel_launch(void* const* d_in, const int* in_sizes, int n_in,
                              void* d_out, int out_size, void* d_ws, size_t ws_size,
                              hipStream_t stream) {
    const float* x    = (const float*)d_in[0];
    const void*  ei   = d_in[1];
    const float* W1   = (const float*)d_in[2];
    const float* b1   = (const float*)d_in[3];
    const float* W2   = (const float*)d_in[4];
    const float* b2   = (const float*)d_in[5];
    const float* Wout = (const float*)d_in[6];
    const float* bout = (const float*)d_in[7];
    float* out = (float*)d_out;

    char* ws = (char*)d_ws;
    size_t off = 0;
    auto alloc = [&](size_t bytes) -> void* {
        off = (off + 255) & ~(size_t)255;
        void* p = ws + off;
        off += bytes;
        return p;
    };
    int*   flag      = (int*)alloc(4);
    int*   cnt       = (int*)alloc((size_t)NN * 4);
    int*   cursor    = (int*)alloc((size_t)NN * 4);
    int*   row_start = (int*)alloc((size_t)(NN + 1) * 4);
    int*   bsum      = (int*)alloc(64 * 4);
    int2*  csr       = (int2*)alloc((size_t)NE * 8);
    float* dinv      = (float*)alloc((size_t)NN * 4);
    float* buf1      = (float*)alloc((size_t)NN * HH1 * 4);
    float* buf2      = (float*)alloc((size_t)NN * HH1 * 4);
    (void)ws_size; (void)in_sizes; (void)n_in; (void)out_size;

    constexpr int NB = (NN + 1023) / 1024;   // 49

    detect_kernel<<<1, 1, 0, stream>>>((const unsigned int*)ei, flag);
    init_kernel<<<(NN + 255) / 256, 256, 0, stream>>>(cnt, cursor, NN);
    hist_kernel<<<(NE + 255) / 256, 256, 0, stream>>>(ei, flag, cnt, NE);
    scan_part_kernel<<<NB, 1024, 0, stream>>>(cnt, row_start, dinv, bsum, NN);
    scan_bsum_kernel<<<1, 64, 0, stream>>>(bsum, NB, row_start, NN);
    scan_add_kernel<<<NB, 1024, 0, stream>>>(row_start, bsum, NN);
    place_kernel<<<(NE + 255) / 256, 256, 0, stream>>>(ei, flag, row_start, cursor,
                                                       dinv, csr, NE);
    // gemm1: buf1 = x @ W1   [NN, HH1]
    dim3 g1((HH1 + 63) / 64, (NN + 63) / 64);
    gemm_kernel<false, false><<<g1, 256, 0, stream>>>(x, W1, buf1, nullptr, nullptr,
                                                      NN, HH1, FIN);
    // agg1: buf2 = A_hat @ buf1   [NN, HH1]
    agg_kernel<HH1, 4><<<(NN + 3) / 4, 256, 0, stream>>>(buf1, dinv, row_start, csr, buf2);
    // gemm2: buf1 = relu(buf2 + b1) @ W2  [NN, HH2]
    dim3 g2((HH2 + 63) / 64, (NN + 63) / 64);
    gemm_kernel<true, false><<<g2, 256, 0, stream>>>(buf2, W2, buf1, b1, nullptr,
                                                     NN, HH2, HH1);
    // agg2: buf2 = A_hat @ buf1   [NN, HH2]
    agg_kernel<HH2, 2><<<(NN + 3) / 4, 256, 0, stream>>>(buf1, dinv, row_start, csr, buf2);
    // gemm3: out = relu(buf2 + b2) @ Wout + bout  [NN, NCLS]
    dim3 g3((NCLS + 63) / 64, (NN + 63) / 64);
    gemm_kernel<true, true><<<g3, 256, 0, stream>>>(buf2, Wout, out, b2, bout,
                                                    NN, NCLS, HH2);
}

// Round 3
// 288.285 us; speedup vs baseline: 2.3142x; 1.6327x over previous
//
#include <hip/hip_runtime.h>

// GCN: 3-layer, N=50000, E=800000, F 128->200->100->40, f32 in/out.
// R3: split-bf16 (hi/lo) MFMA GEMMs + layer-1 reassociation (agg before W1):
//   t  = A_hat @ x                    (agg_x: gather f32 x, write t as bf16 hi/lo)
//   h1 = relu(t @ W1 + b1)            (mfma gemm1, epilogue split-write hi/lo)
//   u  = h1 @ W2                      (mfma gemm2, f32 out)
//   h2 = relu(A_hat @ u + b2)         (agg2, epilogue split-write hi/lo)
//   out= h2 @ Wout + bout             (mfma gemm3, f32 out)
// Split GEMM: C = Ahi@Bhi + Ahi@Blo + Alo@Bhi  (error ~2^-16 rel, f32 acc).

#define NN 50000
#define NE 800000

typedef short v8s __attribute__((ext_vector_type(8)));
typedef float f4 __attribute__((ext_vector_type(4)));

static __device__ __forceinline__ ushort bf16rne(float f) {
    unsigned u = __float_as_uint(f);
    return (ushort)((u + 0x7FFFu + ((u >> 16) & 1u)) >> 16);
}
static __device__ __forceinline__ float bf16tof(ushort h) {
    return __uint_as_float(((unsigned)h) << 16);
}

static __device__ __forceinline__ long long edge_at(const void* p, int is64, long long pos) {
    if (is64) return ((const long long*)p)[pos];
    return (long long)((const int*)p)[pos];
}

// int64 edge buffer => odd 32-bit words (upper halves of values < 50000) all 0.
__global__ void detect_kernel(const unsigned int* __restrict__ w, int* __restrict__ flag) {
    int is64 = 1;
    for (int i = 0; i < 32; ++i)
        if (w[2 * i + 1] != 0u) { is64 = 0; break; }
    *flag = is64;
}

__global__ void init_kernel(int* __restrict__ cnt, int* __restrict__ cursor, int n) {
    int i = blockIdx.x * blockDim.x + threadIdx.x;
    if (i < n) { cnt[i] = 0; cursor[i] = 0; }
}

__global__ void hist_kernel(const void* __restrict__ ei, const int* __restrict__ flag,
                            int* __restrict__ cnt, int E) {
    int e = blockIdx.x * blockDim.x + threadIdx.x;
    if (e < E) {
        int is64 = *flag;
        int d = (int)edge_at(ei, is64, (long long)E + e);
        atomicAdd(&cnt[d], 1);
    }
}

// ---- 3-phase exclusive scan over 50000 bins (+ dinv = rsqrt(deg+1)) ----
__global__ __launch_bounds__(1024)
void scan_part_kernel(const int* __restrict__ cnt, int* __restrict__ row_start,
                      float* __restrict__ dinv, int* __restrict__ bsum, int n) {
    __shared__ int sdata[1024];
    const int t = threadIdx.x;
    const int i = blockIdx.x * 1024 + t;
    int v = (i < n) ? cnt[i] : 0;
    if (i < n) dinv[i] = rsqrtf((float)(v + 1));
    sdata[t] = v;
    __syncthreads();
    #pragma unroll
    for (int o = 1; o < 1024; o <<= 1) {
        int tv = (t >= o) ? sdata[t - o] : 0;
        __syncthreads();
        sdata[t] += tv;
        __syncthreads();
    }
    if (i < n) row_start[i] = sdata[t] - v;
    if (t == 1023) bsum[blockIdx.x] = sdata[1023];
}

__global__ void scan_bsum_kernel(int* __restrict__ bsum, int nb,
                                 int* __restrict__ row_start, int n) {
    if (threadIdx.x == 0 && blockIdx.x == 0) {
        int acc = 0;
        for (int b = 0; b < nb; ++b) { int v = bsum[b]; bsum[b] = acc; acc += v; }
        row_start[n] = acc;
    }
}

__global__ __launch_bounds__(1024)
void scan_add_kernel(int* __restrict__ row_start, const int* __restrict__ bsum, int n) {
    int i = blockIdx.x * 1024 + threadIdx.x;
    if (i < n) row_start[i] += bsum[blockIdx.x];
}

__global__ void place_kernel(const void* __restrict__ ei, const int* __restrict__ flag,
                             const int* __restrict__ row_start, int* __restrict__ cursor,
                             const float* __restrict__ dinv, int2* __restrict__ csr, int E) {
    int e = blockIdx.x * blockDim.x + threadIdx.x;
    if (e < E) {
        int is64 = *flag;
        int s = (int)edge_at(ei, is64, e);
        int d = (int)edge_at(ei, is64, (long long)E + e);
        int p = atomicAdd(&cursor[d], 1);
        csr[row_start[d] + p] = make_int2(s, __float_as_int(dinv[s] * dinv[d]));
    }
}

// Pack all three weight matrices into MFMA B-fragment order, split hi/lo.
// Layout per layer: elem q = ((tile*KS + s)*512 + lane*8 + j);
//   col = tile*16 + (lane&15); k = s*32 + (lane>>4)*8 + j; 0 outside [K]x[N].
#define PK1 (14 * 4 * 512)
#define PK2 (7 * 7 * 512)
#define PK3 (3 * 4 * 512)
__global__ void pack_kernel(const float* __restrict__ W1, const float* __restrict__ W2,
                            const float* __restrict__ W3,
                            ushort* __restrict__ b1h, ushort* __restrict__ b1l,
                            ushort* __restrict__ b2h, ushort* __restrict__ b2l,
                            ushort* __restrict__ b3h, ushort* __restrict__ b3l) {
    int idx = blockIdx.x * blockDim.x + threadIdx.x;
    const float* W; ushort *oh, *ol; int q, KS, K, N;
    if (idx < PK1)                { W = W1; oh = b1h; ol = b1l; q = idx;              KS = 4; K = 128; N = 200; }
    else if (idx < PK1 + PK2)     { W = W2; oh = b2h; ol = b2l; q = idx - PK1;        KS = 7; K = 200; N = 100; }
    else if (idx < PK1 + PK2+PK3) { W = W3; oh = b3h; ol = b3l; q = idx - PK1 - PK2;  KS = 4; K = 100; N = 40;  }
    else return;
    int tile = q / (KS * 512);
    int rem  = q % (KS * 512);
    int s    = rem / 512;
    int z    = rem % 512;
    int lane = z / 8, j = z % 8;
    int col = tile * 16 + (lane & 15);
    int k   = s * 32 + (lane >> 4) * 8 + j;
    float v = (k < K && col < N) ? W[k * N + col] : 0.f;
    ushort h = bf16rne(v);
    oh[q] = h;
    ol[q] = bf16rne(v - bf16tof(h));
}

// CSR aggregation, wave-per-row (4 waves/block). Lane holds VW f32 cols.
// acc = dinv[row]^2*src[row] + sum_e w_e*src[src_e]; epilogue: optional
// (+bias, relu), then split-write bf16 hi/lo at stride KPAD (zero pad cols).
template <int F, int VW, int KPAD, bool BR>
__global__ __launch_bounds__(256)
void agg_kernel(const float* __restrict__ src, const float* __restrict__ dinv,
                const int* __restrict__ row_start, const int2* __restrict__ csr,
                const float* __restrict__ bias,
                ushort* __restrict__ outhi, ushort* __restrict__ outlo) {
    constexpr int L = F / VW;        // compute lanes
    constexpr int LW = KPAD / VW;    // write lanes (pad -> zeros)
    typedef float fvec __attribute__((ext_vector_type(VW)));
    const int wave = threadIdx.x >> 6;
    const int lane = threadIdx.x & 63;
    const int row = blockIdx.x * 4 + wave;
    if (row >= NN) return;

    fvec acc = (fvec)0.f;
    if (lane < L) {
        const int s0 = row_start[row], s1 = row_start[row + 1];
        const float di = dinv[row];
        acc = *(const fvec*)(src + (size_t)row * F + lane * VW);
        #pragma unroll
        for (int q = 0; q < VW; ++q) acc[q] *= di * di;
        int e = s0;
        for (; e + 4 <= s1; e += 4) {
            int2 c0 = csr[e], c1 = csr[e + 1], c2 = csr[e + 2], c3 = csr[e + 3];
            fvec r0 = *(const fvec*)(src + (size_t)c0.x * F + lane * VW);
            fvec r1 = *(const fvec*)(src + (size_t)c1.x * F + lane * VW);
            fvec r2 = *(const fvec*)(src + (size_t)c2.x * F + lane * VW);
            fvec r3 = *(const fvec*)(src + (size_t)c3.x * F + lane * VW);
            float w0 = __int_as_float(c0.y), w1 = __int_as_float(c1.y);
            float w2 = __int_as_float(c2.y), w3 = __int_as_float(c3.y);
            #pragma unroll
            for (int q = 0; q < VW; ++q) {
                acc[q] = fmaf(r0[q], w0, acc[q]);
                acc[q] = fmaf(r1[q], w1, acc[q]);
                acc[q] = fmaf(r2[q], w2, acc[q]);
                acc[q] = fmaf(r3[q], w3, acc[q]);
            }
        }
        for (; e < s1; ++e) {
            int2 c = csr[e];
            fvec r = *(const fvec*)(src + (size_t)c.x * F + lane * VW);
            float w = __int_as_float(c.y);
            #pragma unroll
            for (int q = 0; q < VW; ++q) acc[q] = fmaf(r[q], w, acc[q]);
        }
    }
    if (lane < LW) {
        ushort hv[VW], lv[VW];
        #pragma unroll
        for (int q = 0; q < VW; ++q) {
            float v = (lane < L) ? acc[q] : 0.f;
            if constexpr (BR) { if (lane < L) v = fmaxf(v + bias[lane * VW + q], 0.f); }
            ushort h = bf16rne(v);
            hv[q] = h;
            lv[q] = bf16rne(v - bf16tof(h));
        }
        size_t base = (size_t)row * KPAD + lane * VW;
        if constexpr (VW == 4) {
            *(ushort4*)(outhi + base) = make_ushort4(hv[0], hv[1], hv[2], hv[3]);
            *(ushort4*)(outlo + base) = make_ushort4(lv[0], lv[1], lv[2], lv[3]);
        } else {
            *(ushort2*)(outhi + base) = make_ushort2(hv[0], hv[1]);
            *(ushort2*)(outlo + base) = make_ushort2(lv[0], lv[1]);
        }
    }
}

// Split-bf16 MFMA GEMM. Block = 256 thr = 4 waves; wave w owns rows
// [blk*64 + w*16, +16), all NT n-tiles. A frags direct from global (16B/lane),
// B frags from pre-packed arrays (L2-resident). 3 MFMA per tile per k-step.
// MODE 0: C=f32 (guard col<N). 1: f32 + bias. 2: relu(+bias), split hi/lo
// write at stride NPAD (covers all NT*16 cols -> pad zeroed).
template <int NT, int KS, int MODE>
__global__ __launch_bounds__(256)
void mfma_gemm(const ushort* __restrict__ Ahi, const ushort* __restrict__ Alo,
               const ushort* __restrict__ Bhi, const ushort* __restrict__ Blo,
               float* __restrict__ Cf, ushort* __restrict__ Chi, ushort* __restrict__ Clo,
               const float* __restrict__ bias, int M, int N, int NPAD) {
    constexpr int KP = KS * 32;
    const int tid = threadIdx.x, w = tid >> 6, l = tid & 63;
    const int arow = blockIdx.x * 64 + w * 16 + (l & 15);
    const int kg = l >> 4;
    const bool aok = arow < M;
    f4 acc[NT];
    #pragma unroll
    for (int t = 0; t < NT; ++t) acc[t] = (f4)0.f;
    const v8s zz = (v8s)0;
    const ushort* pah = Ahi + (size_t)arow * KP + kg * 8;
    const ushort* pal = Alo + (size_t)arow * KP + kg * 8;

    for (int s = 0; s < KS; ++s) {
        v8s ah = aok ? *(const v8s*)(pah + s * 32) : zz;
        v8s al = aok ? *(const v8s*)(pal + s * 32) : zz;
        #pragma unroll
        for (int t = 0; t < NT; ++t) {
            v8s bh = *(const v8s*)(Bhi + ((size_t)(t * KS + s) * 64 + l) * 8);
            v8s bl = *(const v8s*)(Blo + ((size_t)(t * KS + s) * 64 + l) * 8);
            acc[t] = __builtin_amdgcn_mfma_f32_16x16x32_bf16(ah, bh, acc[t], 0, 0, 0);
            acc[t] = __builtin_amdgcn_mfma_f32_16x16x32_bf16(ah, bl, acc[t], 0, 0, 0);
            acc[t] = __builtin_amdgcn_mfma_f32_16x16x32_bf16(al, bh, acc[t], 0, 0, 0);
        }
    }
    // C/D: col = lane&15, row = (lane>>4)*4 + reg  (HW-verified layout)
    const int crow0 = blockIdx.x * 64 + w * 16 + (l >> 4) * 4;
    #pragma unroll
    for (int t = 0; t < NT; ++t) {
        int col = t * 16 + (l & 15);
        #pragma unroll
        for (int r = 0; r < 4; ++r) {
            int row = crow0 + r;
            if (row >= M) continue;
            float v = acc[t][r];
            if constexpr (MODE == 0) {
                if (col < N) Cf[(size_t)row * N + col] = v;
            } else if constexpr (MODE == 1) {
                if (col < N) Cf[(size_t)row * N + col] = v + bias[col];
            } else {
                float o = (col < N) ? fmaxf(v + bias[col], 0.f) : 0.f;
                ushort h = bf16rne(o);
                Chi[(size_t)row * NPAD + col] = h;
                Clo[(size_t)row * NPAD + col] = bf16rne(o - bf16tof(h));
            }
        }
    }
}

extern "C" void kernel_launch(void* const* d_in, const int* in_sizes, int n_in,
                              void* d_out, int out_size, void* d_ws, size_t ws_size,
                              hipStream_t stream) {
    const float* x    = (const float*)d_in[0];
    const void*  ei   = d_in[1];
    const float* W1   = (const float*)d_in[2];
    const float* b1   = (const float*)d_in[3];
    const float* W2   = (const float*)d_in[4];
    const float* b2   = (const float*)d_in[5];
    const float* Wout = (const float*)d_in[6];
    const float* bout = (const float*)d_in[7];
    float* out = (float*)d_out;

    char* ws = (char*)d_ws;
    size_t off = 0;
    auto alloc = [&](size_t bytes) -> void* {
        off = (off + 255) & ~(size_t)255;
        void* p = ws + off;
        off += bytes;
        return p;
    };
    int*    flag      = (int*)alloc(4);
    int*    cnt       = (int*)alloc((size_t)NN * 4);
    int*    cursor    = (int*)alloc((size_t)NN * 4);
    int*    row_start = (int*)alloc((size_t)(NN + 1) * 4);
    int*    bsum      = (int*)alloc(64 * 4);
    float*  dinv      = (float*)alloc((size_t)NN * 4);
    int2*   csr       = (int2*)alloc((size_t)NE * 8);
    ushort* thi       = (ushort*)alloc((size_t)NN * 128 * 2);   // t = A_hat@x; later h2
    ushort* tlo       = (ushort*)alloc((size_t)NN * 128 * 2);
    ushort* h1hi      = (ushort*)alloc((size_t)NN * 224 * 2);
    ushort* h1lo      = (ushort*)alloc((size_t)NN * 224 * 2);
    float*  buff      = (float*)alloc((size_t)NN * 100 * 4);    // u = h1@W2
    ushort* b1h       = (ushort*)alloc((size_t)PK1 * 2);
    ushort* b1l       = (ushort*)alloc((size_t)PK1 * 2);
    ushort* b2h       = (ushort*)alloc((size_t)PK2 * 2);
    ushort* b2l       = (ushort*)alloc((size_t)PK2 * 2);
    ushort* b3h       = (ushort*)alloc((size_t)PK3 * 2);
    ushort* b3l       = (ushort*)alloc((size_t)PK3 * 2);
    ushort* h2hi = thi, *h2lo = tlo;   // t dead after gemm1; reuse for h2
    (void)ws_size; (void)in_sizes; (void)n_in; (void)out_size;

    constexpr int NB = (NN + 1023) / 1024;   // 49

    detect_kernel<<<1, 1, 0, stream>>>((const unsigned int*)ei, flag);
    init_kernel<<<(NN + 255) / 256, 256, 0, stream>>>(cnt, cursor, NN);
    hist_kernel<<<(NE + 255) / 256, 256, 0, stream>>>(ei, flag, cnt, NE);
    scan_part_kernel<<<NB, 1024, 0, stream>>>(cnt, row_start, dinv, bsum, NN);
    scan_bsum_kernel<<<1, 64, 0, stream>>>(bsum, NB, row_start, NN);
    scan_add_kernel<<<NB, 1024, 0, stream>>>(row_start, bsum, NN);
    place_kernel<<<(NE + 255) / 256, 256, 0, stream>>>(ei, flag, row_start, cursor,
                                                       dinv, csr, NE);
    pack_kernel<<<(PK1 + PK2 + PK3 + 255) / 256, 256, 0, stream>>>(
        W1, W2, Wout, b1h, b1l, b2h, b2l, b3h, b3l);

    const int GA = (NN + 3) / 4;        // agg blocks (4 rows each)
    const int GG = (NN + 63) / 64;      // gemm blocks (64 rows each)

    // t = A_hat @ x  (gather f32 x, split-write bf16 hi/lo, no bias/relu)
    agg_kernel<128, 2, 128, false><<<GA, 256, 0, stream>>>(
        x, dinv, row_start, csr, nullptr, thi, tlo);
    // h1 = relu(t@W1 + b1), split-write at stride 224
    mfma_gemm<14, 4, 2><<<GG, 256, 0, stream>>>(
        thi, tlo, b1h, b1l, nullptr, h1hi, h1lo, b1, NN, 200, 224);
    // u = h1 @ W2  (f32 out, stride 100)
    mfma_gemm<7, 7, 0><<<GG, 256, 0, stream>>>(
        h1hi, h1lo, b2h, b2l, buff, nullptr, nullptr, nullptr, NN, 100, 0);
    // h2 = relu(A_hat@u + b2), split-write at stride 128
    agg_kernel<100, 2, 128, true><<<GA, 256, 0, stream>>>(
        buff, dinv, row_start, csr, b2, h2hi, h2lo);
    // out = h2 @ Wout + bout
    mfma_gemm<3, 4, 1><<<GG, 256, 0, stream>>>(
        h2hi, h2lo, b3h, b3l, out, nullptr, nullptr, bout, NN, 40, 0);
}

// Round 4
// 229.679 us; speedup vs baseline: 2.9047x; 1.2552x over previous
//
#include <hip/hip_runtime.h>

// GCN: 3-layer, N=50000, E=800000, F 128->200->100->40, f32 in/out.
// R4: full-bf16 storage (f32 accumulation), single-MFMA GEMMs, bf16 gathers.
//   xb = bf16(x)
//   t  = A_hat @ xb            (agg1: bf16 gather, f32 acc, bf16 out @128)
//   h1 = relu(t @ W1 + b1)     (mfma gemm1, bf16 out @224)
//   u  = h1 @ W2               (mfma gemm2, bf16 out @112)
//   h2 = relu(A_hat @ u + b2)  (agg2: bf16 gather, f32 acc, bf16 out @128)
//   out= h2 @ Wout + bout      (mfma gemm3, f32 out)
// R3 counters: aggs gather-traffic-bound (FETCH ~= 8 XCD x source size);
// bf16 halves the gathered bytes. Comparison floor is 1 bf16 ULP anyway.

#define NN 50000
#define NE 800000

typedef short v8s __attribute__((ext_vector_type(8)));
typedef float f4 __attribute__((ext_vector_type(4)));

static __device__ __forceinline__ ushort bf16rne(float f) {
    unsigned u = __float_as_uint(f);
    return (ushort)((u + 0x7FFFu + ((u >> 16) & 1u)) >> 16);
}
static __device__ __forceinline__ float bf16tof(ushort h) {
    return __uint_as_float(((unsigned)h) << 16);
}

static __device__ __forceinline__ long long edge_at(const void* p, int is64, long long pos) {
    if (is64) return ((const long long*)p)[pos];
    return (long long)((const int*)p)[pos];
}

// Weight pack layout (B-fragment order, bf16):
//   elem q = (tile*KS + s)*512 + lane*8 + j
//   col = tile*16 + (lane&15); k = s*32 + (lane>>4)*8 + j; 0 outside [K]x[N].
#define PK1 (14 * 4 * 512)
#define PK2 (7 * 7 * 512)
#define PK3 (3 * 4 * 512)
#define CVT_BLKS ((NN * 128 / 8 + 255) / 256)          // 3125
#define INIT_BLKS ((NN + 255) / 256)                   // 196
#define PACK_BLKS ((PK1 + PK2 + PK3 + 255) / 256)      // 234

// Fused prep: x->bf16 convert | cnt/cursor zero | weight pack | edge-dtype detect.
__global__ __launch_bounds__(256)
void prep_kernel(const float* __restrict__ x, const float* __restrict__ W1,
                 const float* __restrict__ W2, const float* __restrict__ W3,
                 ushort* __restrict__ xb,
                 ushort* __restrict__ b1p, ushort* __restrict__ b2p,
                 ushort* __restrict__ b3p,
                 int* __restrict__ flag, int* __restrict__ cnt,
                 int* __restrict__ cursor, const unsigned int* __restrict__ eiw) {
    int b = blockIdx.x;
    if (b < CVT_BLKS) {                       // x -> bf16, 8 elems/thread
        size_t i0 = ((size_t)b * 256 + threadIdx.x) * 8;
        if (i0 + 8 <= (size_t)NN * 128) {
            float4 v0 = *(const float4*)(x + i0);
            float4 v1 = *(const float4*)(x + i0 + 4);
            ushort4 o0 = make_ushort4(bf16rne(v0.x), bf16rne(v0.y), bf16rne(v0.z), bf16rne(v0.w));
            ushort4 o1 = make_ushort4(bf16rne(v1.x), bf16rne(v1.y), bf16rne(v1.z), bf16rne(v1.w));
            *(ushort4*)(xb + i0) = o0;
            *(ushort4*)(xb + i0 + 4) = o1;
        }
        return;
    }
    b -= CVT_BLKS;
    if (b < INIT_BLKS) {
        int i = b * 256 + threadIdx.x;
        if (i < NN) { cnt[i] = 0; cursor[i] = 0; }
        return;
    }
    b -= INIT_BLKS;
    if (b < PACK_BLKS) {
        int idx = b * 256 + threadIdx.x;
        const float* W; ushort* o; int q, KS, K, N;
        if (idx < PK1)                  { W = W1; o = b1p; q = idx;             KS = 4; K = 128; N = 200; }
        else if (idx < PK1 + PK2)       { W = W2; o = b2p; q = idx - PK1;       KS = 7; K = 200; N = 100; }
        else if (idx < PK1 + PK2 + PK3) { W = W3; o = b3p; q = idx - PK1 - PK2; KS = 4; K = 100; N = 40;  }
        else return;
        int tile = q / (KS * 512);
        int rem  = q % (KS * 512);
        int s    = rem / 512;
        int z    = rem % 512;
        int lane = z / 8, j = z % 8;
        int col = tile * 16 + (lane & 15);
        int k   = s * 32 + (lane >> 4) * 8 + j;
        o[q] = bf16rne((k < K && col < N) ? W[k * N + col] : 0.f);
        return;
    }
    // last block: detect int64 vs int32 edge buffer
    if (threadIdx.x == 0) {
        int is64 = 1;
        for (int i = 0; i < 32; ++i)
            if (eiw[2 * i + 1] != 0u) { is64 = 0; break; }
        *flag = is64;
    }
}

__global__ void hist_kernel(const void* __restrict__ ei, const int* __restrict__ flag,
                            int* __restrict__ cnt, int E) {
    int e = blockIdx.x * blockDim.x + threadIdx.x;
    if (e < E) {
        int is64 = *flag;
        int d = (int)edge_at(ei, is64, (long long)E + e);
        atomicAdd(&cnt[d], 1);
    }
}

// ---- 3-phase exclusive scan over 50000 bins (+ dinv = rsqrt(deg+1)) ----
__global__ __launch_bounds__(1024)
void scan_part_kernel(const int* __restrict__ cnt, int* __restrict__ row_start,
                      float* __restrict__ dinv, int* __restrict__ bsum, int n) {
    __shared__ int sdata[1024];
    const int t = threadIdx.x;
    const int i = blockIdx.x * 1024 + t;
    int v = (i < n) ? cnt[i] : 0;
    if (i < n) dinv[i] = rsqrtf((float)(v + 1));
    sdata[t] = v;
    __syncthreads();
    #pragma unroll
    for (int o = 1; o < 1024; o <<= 1) {
        int tv = (t >= o) ? sdata[t - o] : 0;
        __syncthreads();
        sdata[t] += tv;
        __syncthreads();
    }
    if (i < n) row_start[i] = sdata[t] - v;
    if (t == 1023) bsum[blockIdx.x] = sdata[1023];
}

__global__ void scan_bsum_kernel(int* __restrict__ bsum, int nb,
                                 int* __restrict__ row_start, int n) {
    if (threadIdx.x == 0 && blockIdx.x == 0) {
        int acc = 0;
        for (int b = 0; b < nb; ++b) { int v = bsum[b]; bsum[b] = acc; acc += v; }
        row_start[n] = acc;
    }
}

__global__ __launch_bounds__(1024)
void scan_add_kernel(int* __restrict__ row_start, const int* __restrict__ bsum, int n) {
    int i = blockIdx.x * 1024 + threadIdx.x;
    if (i < n) row_start[i] += bsum[blockIdx.x];
}

__global__ void place_kernel(const void* __restrict__ ei, const int* __restrict__ flag,
                             const int* __restrict__ row_start, int* __restrict__ cursor,
                             const float* __restrict__ dinv, int2* __restrict__ csr, int E) {
    int e = blockIdx.x * blockDim.x + threadIdx.x;
    if (e < E) {
        int is64 = *flag;
        int s = (int)edge_at(ei, is64, e);
        int d = (int)edge_at(ei, is64, (long long)E + e);
        int p = atomicAdd(&cursor[d], 1);
        csr[row_start[d] + p] = make_int2(s, __float_as_int(dinv[s] * dinv[d]));
    }
}

// CSR aggregation, wave-per-row (4 waves/block), bf16 source, f32 accum,
// bf16 output. Lane holds 2 columns. out written at stride KPAD, pad zeroed.
template <int F, int SST, int KPAD, bool BR>
__global__ __launch_bounds__(256)
void agg_kernel(const ushort* __restrict__ src, const float* __restrict__ dinv,
                const int* __restrict__ row_start, const int2* __restrict__ csr,
                const float* __restrict__ bias, ushort* __restrict__ outp) {
    constexpr int L = F / 2;          // compute lanes
    constexpr int LW = KPAD / 2;      // write lanes
    const int wave = threadIdx.x >> 6;
    const int lane = threadIdx.x & 63;
    const int row = blockIdx.x * 4 + wave;
    if (row >= NN) return;

    float a0 = 0.f, a1 = 0.f;
    if (lane < L) {
        const int s0 = row_start[row], s1 = row_start[row + 1];
        const float di = dinv[row];
        ushort2 sv = *(const ushort2*)(src + (size_t)row * SST + lane * 2);
        a0 = di * di * bf16tof(sv.x);
        a1 = di * di * bf16tof(sv.y);
        int e = s0;
        for (; e + 4 <= s1; e += 4) {
            int2 c0 = csr[e], c1 = csr[e + 1], c2 = csr[e + 2], c3 = csr[e + 3];
            ushort2 r0 = *(const ushort2*)(src + (size_t)c0.x * SST + lane * 2);
            ushort2 r1 = *(const ushort2*)(src + (size_t)c1.x * SST + lane * 2);
            ushort2 r2 = *(const ushort2*)(src + (size_t)c2.x * SST + lane * 2);
            ushort2 r3 = *(const ushort2*)(src + (size_t)c3.x * SST + lane * 2);
            float w0 = __int_as_float(c0.y), w1 = __int_as_float(c1.y);
            float w2 = __int_as_float(c2.y), w3 = __int_as_float(c3.y);
            a0 = fmaf(bf16tof(r0.x), w0, a0); a1 = fmaf(bf16tof(r0.y), w0, a1);
            a0 = fmaf(bf16tof(r1.x), w1, a0); a1 = fmaf(bf16tof(r1.y), w1, a1);
            a0 = fmaf(bf16tof(r2.x), w2, a0); a1 = fmaf(bf16tof(r2.y), w2, a1);
            a0 = fmaf(bf16tof(r3.x), w3, a0); a1 = fmaf(bf16tof(r3.y), w3, a1);
        }
        for (; e < s1; ++e) {
            int2 c = csr[e];
            ushort2 r = *(const ushort2*)(src + (size_t)c.x * SST + lane * 2);
            float w = __int_as_float(c.y);
            a0 = fmaf(bf16tof(r.x), w, a0);
            a1 = fmaf(bf16tof(r.y), w, a1);
        }
    }
    if (lane < LW) {
        float v0 = a0, v1 = a1;
        if constexpr (BR) {
            if (lane < L) {
                v0 = fmaxf(v0 + bias[lane * 2], 0.f);
                v1 = fmaxf(v1 + bias[lane * 2 + 1], 0.f);
            }
        }
        *(ushort2*)(outp + (size_t)row * KPAD + lane * 2) =
            make_ushort2(bf16rne(v0), bf16rne(v1));
    }
}

// bf16 MFMA GEMM, 4 waves/block, wave w owns rows [blk*64+w*16, +16), all NT
// n-tiles. A frags direct from global (16B/lane), B pre-packed (L2-resident).
// MODE 0: f32 + bias (guard col<N). 1: bf16 relu(+bias) @NPAD (pad zeroed).
// 2: bf16 plain @NPAD (pad zeroed).
template <int NT, int KS, int MODE>
__global__ __launch_bounds__(256)
void mfma_gemm(const ushort* __restrict__ A, const ushort* __restrict__ B,
               float* __restrict__ Cf, ushort* __restrict__ Cb,
               const float* __restrict__ bias, int M, int N, int NPAD) {
    constexpr int KP = KS * 32;
    const int tid = threadIdx.x, w = tid >> 6, l = tid & 63;
    const int arow = blockIdx.x * 64 + w * 16 + (l & 15);
    const int kg = l >> 4;
    const bool aok = arow < M;
    f4 acc[NT];
    #pragma unroll
    for (int t = 0; t < NT; ++t) acc[t] = (f4)0.f;
    const v8s zz = (v8s)0;
    const ushort* pa = A + (size_t)arow * KP + kg * 8;

    for (int s = 0; s < KS; ++s) {
        v8s a = aok ? *(const v8s*)(pa + s * 32) : zz;
        #pragma unroll
        for (int t = 0; t < NT; ++t) {
            v8s b = *(const v8s*)(B + ((size_t)(t * KS + s) * 64 + l) * 8);
            acc[t] = __builtin_amdgcn_mfma_f32_16x16x32_bf16(a, b, acc[t], 0, 0, 0);
        }
    }
    // C/D: col = lane&15, row = (lane>>4)*4 + reg
    const int crow0 = blockIdx.x * 64 + w * 16 + (l >> 4) * 4;
    #pragma unroll
    for (int t = 0; t < NT; ++t) {
        int col = t * 16 + (l & 15);
        #pragma unroll
        for (int r = 0; r < 4; ++r) {
            int row = crow0 + r;
            if (row >= M) continue;
            float v = acc[t][r];
            if constexpr (MODE == 0) {
                if (col < N) Cf[(size_t)row * N + col] = v + bias[col];
            } else if constexpr (MODE == 1) {
                float o = (col < N) ? fmaxf(v + bias[col], 0.f) : 0.f;
                Cb[(size_t)row * NPAD + col] = bf16rne(o);
            } else {
                float o = (col < N) ? v : 0.f;
                Cb[(size_t)row * NPAD + col] = bf16rne(o);
            }
        }
    }
}

extern "C" void kernel_launch(void* const* d_in, const int* in_sizes, int n_in,
                              void* d_out, int out_size, void* d_ws, size_t ws_size,
                              hipStream_t stream) {
    const float* x    = (const float*)d_in[0];
    const void*  ei   = d_in[1];
    const float* W1   = (const float*)d_in[2];
    const float* b1   = (const float*)d_in[3];
    const float* W2   = (const float*)d_in[4];
    const float* b2   = (const float*)d_in[5];
    const float* Wout = (const float*)d_in[6];
    const float* bout = (const float*)d_in[7];
    float* out = (float*)d_out;

    char* ws = (char*)d_ws;
    size_t off = 0;
    auto alloc = [&](size_t bytes) -> void* {
        off = (off + 255) & ~(size_t)255;
        void* p = ws + off;
        off += bytes;
        return p;
    };
    int*    flag      = (int*)alloc(4);
    int*    cnt       = (int*)alloc((size_t)NN * 4);
    int*    cursor    = (int*)alloc((size_t)NN * 4);
    int*    row_start = (int*)alloc((size_t)(NN + 1) * 4);
    int*    bsum      = (int*)alloc(64 * 4);
    float*  dinv      = (float*)alloc((size_t)NN * 4);
    int2*   csr       = (int2*)alloc((size_t)NE * 8);
    ushort* xb        = (ushort*)alloc((size_t)NN * 128 * 2);
    ushort* tbuf      = (ushort*)alloc((size_t)NN * 128 * 2);
    ushort* h1        = (ushort*)alloc((size_t)NN * 224 * 2);
    ushort* u         = (ushort*)alloc((size_t)NN * 112 * 2);
    ushort* h2        = (ushort*)alloc((size_t)NN * 128 * 2);
    ushort* b1p       = (ushort*)alloc((size_t)PK1 * 2);
    ushort* b2p       = (ushort*)alloc((size_t)PK2 * 2);
    ushort* b3p       = (ushort*)alloc((size_t)PK3 * 2);
    (void)ws_size; (void)in_sizes; (void)n_in; (void)out_size;

    constexpr int NB = (NN + 1023) / 1024;   // 49
    const int PREP_BLKS = CVT_BLKS + INIT_BLKS + PACK_BLKS + 1;

    prep_kernel<<<PREP_BLKS, 256, 0, stream>>>(x, W1, W2, Wout, xb, b1p, b2p, b3p,
                                               flag, cnt, cursor,
                                               (const unsigned int*)ei);
    hist_kernel<<<(NE + 255) / 256, 256, 0, stream>>>(ei, flag, cnt, NE);
    scan_part_kernel<<<NB, 1024, 0, stream>>>(cnt, row_start, dinv, bsum, NN);
    scan_bsum_kernel<<<1, 64, 0, stream>>>(bsum, NB, row_start, NN);
    scan_add_kernel<<<NB, 1024, 0, stream>>>(row_start, bsum, NN);
    place_kernel<<<(NE + 255) / 256, 256, 0, stream>>>(ei, flag, row_start, cursor,
                                                       dinv, csr, NE);

    const int GA = (NN + 3) / 4;        // agg blocks (4 rows each)
    const int GG = (NN + 63) / 64;      // gemm blocks (64 rows each)

    // t = A_hat @ xb  (bf16 gather, bf16 out @128)
    agg_kernel<128, 128, 128, false><<<GA, 256, 0, stream>>>(
        xb, dinv, row_start, csr, nullptr, tbuf);
    // h1 = relu(t@W1 + b1)  (bf16 out @224)
    mfma_gemm<14, 4, 1><<<GG, 256, 0, stream>>>(
        tbuf, b1p, nullptr, h1, b1, NN, 200, 224);
    // u = h1 @ W2  (bf16 out @112)
    mfma_gemm<7, 7, 2><<<GG, 256, 0, stream>>>(
        h1, b2p, nullptr, u, nullptr, NN, 100, 112);
    // h2 = relu(A_hat@u + b2)  (bf16 gather @112, bf16 out @128)
    agg_kernel<100, 112, 128, true><<<GA, 256, 0, stream>>>(
        u, dinv, row_start, csr, b2, h2);
    // out = h2 @ Wout + bout  (f32 out)
    mfma_gemm<3, 4, 0><<<GG, 256, 0, stream>>>(
        h2, b3p, out, nullptr, bout, NN, 40, 0);
}